// Round 5
// baseline (382.660 us; speedup 1.0000x reference)
//
#include <hip/hip_runtime.h>

// Problem constants
#define B_SZ   2
#define S_LEN  2048
#define DMODEL 1024
#define HID    256
#define NH     4
#define DH     64
#define DFF    512
#define LN_EPS 1e-5f
#define ATT_SCALE 0.0625f   // 1/sqrt(HID)

typedef __attribute__((ext_vector_type(8))) short bf16x8;
typedef __attribute__((ext_vector_type(4))) float f32x4;

// fp32 -> bf16 RNE
static __device__ __forceinline__ unsigned short f2bf(float x) {
    union { float f; unsigned u; } v; v.f = x;
    unsigned r = v.u + 0x7FFFu + ((v.u >> 16) & 1u);
    return (unsigned short)(r >> 16);
}
static __device__ __forceinline__ unsigned packbf(float a, float b) {
    return (unsigned)f2bf(a) | ((unsigned)f2bf(b) << 16);
}
static __device__ __forceinline__ float bf2f(unsigned short h) {
    union { unsigned u; float f; } v; v.u = ((unsigned)h) << 16; return v.f;
}
// LDS swizzle for 128B rows (bits 4-6 ^= row bits 0-2), involution
static __device__ __forceinline__ int swz(int byte) {
    return byte ^ ((byte >> 3) & 0x70);
}

// ---------------------------------------------------------------------------
// bf16 GEMM: 64x64 tile, 1 wave/block, BK=64, single LDS buffer,
// register-prefetch (T14): load k-step t+1 into VGPRs, compute t, ds_write.
// No barriers (single wave; per-wave DS ops are in-order).
// A [M][K] bf16 row-major, W [N][K] bf16 (pre-transposed).
// ---------------------------------------------------------------------------
__device__ __forceinline__ void gload16(const unsigned short* __restrict__ G,
                                        int row0, int k0, int K, int lane, uint4 r[8])
{
    #pragma unroll
    for (int j = 0; j < 8; ++j) {
        int o = (j * 64 + lane) * 16;      // byte offset in 8KB tile
        r[j] = *(const uint4*)((const char*)G +
                ((size_t)(row0 + (o >> 7)) * K + k0) * 2 + (o & 127));
    }
}
__device__ __forceinline__ void gwrite16(char* lds, int lane, const uint4 r[8])
{
    #pragma unroll
    for (int j = 0; j < 8; ++j) {
        int o = (j * 64 + lane) * 16;
        *(uint4*)(lds + (o ^ ((o >> 3) & 0x70))) = r[j];
    }
}

__device__ __forceinline__ void gcompute(const char* As, const char* Bs,
                                         f32x4 acc[4][4], int lr, int lg)
{
    #pragma unroll
    for (int ks = 0; ks < 2; ++ks) {
        bf16x8 af[4], bfv[4];
        #pragma unroll
        for (int m = 0; m < 4; ++m) {
            int r = m * 16 + lr;
            af[m] = *(const bf16x8*)(As + ((r * 128 + ks * 64 + lg * 16) ^ ((lr & 7) << 4)));
        }
        #pragma unroll
        for (int n = 0; n < 4; ++n) {
            int r = n * 16 + lr;
            bfv[n] = *(const bf16x8*)(Bs + ((r * 128 + ks * 64 + lg * 16) ^ ((lr & 7) << 4)));
        }
        #pragma unroll
        for (int m = 0; m < 4; ++m)
            #pragma unroll
            for (int n = 0; n < 4; ++n)
                acc[m][n] = __builtin_amdgcn_mfma_f32_16x16x32_bf16(
                    af[m], bfv[n], acc[m][n], 0, 0, 0);
    }
}

__device__ __forceinline__ void gemm64_core(
    const unsigned short* __restrict__ A, const unsigned short* __restrict__ W,
    const float* __restrict__ bias, const float* __restrict__ residf,
    const unsigned short* __restrict__ residb,
    float* __restrict__ Cf, unsigned short* __restrict__ Cb,
    int N, int K, int relu, int row0, int col0)
{
    __shared__ char As[8192], Bs[8192];
    const int lane = threadIdx.x;
    const int lr = lane & 15, lg = lane >> 4;

    f32x4 acc[4][4] = {};
    uint4 ra[8], rb[8];

    gload16(A, row0, 0, K, lane, ra);
    gload16(W, col0, 0, K, lane, rb);
    gwrite16(As, lane, ra);
    gwrite16(Bs, lane, rb);

    const int NK = K >> 6;
    for (int ks = 0; ks < NK; ++ks) {
        if (ks + 1 < NK) {
            gload16(A, row0, (ks + 1) * 64, K, lane, ra);
            gload16(W, col0, (ks + 1) * 64, K, lane, rb);
        }
        gcompute(As, Bs, acc, lr, lg);
        if (ks + 1 < NK) {
            gwrite16(As, lane, ra);
            gwrite16(Bs, lane, rb);
        }
    }

    // epilogue: row = mf*16 + lg*4 + r, col = nf*16 + lr
    #pragma unroll
    for (int mf = 0; mf < 4; ++mf) {
        #pragma unroll
        for (int nf = 0; nf < 4; ++nf) {
            #pragma unroll
            for (int r = 0; r < 4; ++r) {
                int row = row0 + mf * 16 + lg * 4 + r;
                int col = col0 + nf * 16 + lr;
                float v2 = acc[mf][nf][r] + bias[col];
                if (residf) v2 += residf[(size_t)row * N + col];
                if (residb) v2 += bf2f(residb[(size_t)row * N + col]);
                if (relu)   v2 = fmaxf(v2, 0.f);
                if (Cb) Cb[(size_t)row * N + col] = f2bf(v2);
                else    Cf[(size_t)row * N + col] = v2;
            }
        }
    }
}

__global__ __launch_bounds__(64) void gemm_b16(
    const unsigned short* __restrict__ A, const unsigned short* __restrict__ W,
    const float* __restrict__ bias, const float* __restrict__ residf,
    const unsigned short* __restrict__ residb,
    float* __restrict__ Cf, unsigned short* __restrict__ Cb,
    int N, int K, int relu)
{
    gemm64_core(A, W, bias, residf, residb, Cf, Cb, N, K, relu,
                blockIdx.x * 64, blockIdx.y * 64);
}

__global__ __launch_bounds__(64) void gemm_qkv3(
    const unsigned short* __restrict__ qkvb, const unsigned short* __restrict__ Wt,
    const float* __restrict__ bq, const float* __restrict__ bk,
    const float* __restrict__ bv, unsigned short* __restrict__ outb)
{
    const int z = blockIdx.z;
    const unsigned short* A = qkvb + (size_t)z * 4096 * 1024;
    const unsigned short* W = Wt + (size_t)z * 262144;
    const float* bias = (z == 0) ? bq : ((z == 1) ? bk : bv);
    unsigned short* Cb = outb + (size_t)z * 4096 * 256;
    gemm64_core(A, W, bias, nullptr, nullptr, nullptr, Cb, 256, 1024, 0,
                blockIdx.x * 64, blockIdx.y * 64);
}

// ---------------------------------------------------------------------------
// Weight prep: fp32 [K][N] -> bf16 [N][K], all 6 weights in one launch.
// ---------------------------------------------------------------------------
__global__ __launch_bounds__(256) void prep_w(
    const float* __restrict__ Wq, const float* __restrict__ Wk,
    const float* __restrict__ Wv, const float* __restrict__ Wo,
    const float* __restrict__ W1, const float* __restrict__ W2,
    unsigned short* __restrict__ Wt)
{
    __shared__ float tile[64][65];
    const int bid = blockIdx.x;
    const float* src; int K, N; size_t off; int local;
    if (bid < 64)       { src = Wq; K = 1024; N = 256;  off = 0;        local = bid; }
    else if (bid < 128) { src = Wk; K = 1024; N = 256;  off = 262144;  local = bid - 64; }
    else if (bid < 192) { src = Wv; K = 1024; N = 256;  off = 524288;  local = bid - 128; }
    else if (bid < 256) { src = Wo; K = 256;  N = 1024; off = 786432;  local = bid - 192; }
    else if (bid < 384) { src = W1; K = 1024; N = 512;  off = 1048576; local = bid - 256; }
    else                { src = W2; K = 512;  N = 1024; off = 1572864; local = bid - 384; }
    const int nkt = K >> 6;
    const int k0 = (local % nkt) * 64, n0 = (local / nkt) * 64;
    const int t = threadIdx.x;
    #pragma unroll
    for (int i = 0; i < 16; ++i) {
        int id = t + i * 256;
        int r = id >> 6, c = id & 63;
        tile[r][c] = src[(size_t)(k0 + r) * N + n0 + c];
    }
    __syncthreads();
    unsigned* Wt32 = (unsigned*)(Wt + off);
    #pragma unroll
    for (int i = 0; i < 8; ++i) {
        int id = t + i * 256;
        int n = id >> 5, ku = id & 31;
        Wt32[((size_t)(n0 + n) * K + k0) / 2 + ku] =
            packbf(tile[2 * ku][n], tile[2 * ku + 1][n]);
    }
}

// q,k,v fp32 -> bf16 contiguous [3][4096][1024]
__global__ __launch_bounds__(256) void prep_qkv(
    const float* __restrict__ q, const float* __restrict__ k,
    const float* __restrict__ v, unsigned short* __restrict__ qkvb)
{
    const float* src = blockIdx.z == 0 ? q : (blockIdx.z == 1 ? k : v);
    uint2* dst = (uint2*)(qkvb + (size_t)blockIdx.z * 4096 * 1024);
    int idx = blockIdx.x * 256 + threadIdx.x;
    float4 x = ((const float4*)src)[idx];
    dst[idx] = make_uint2(packbf(x.x, x.y), packbf(x.z, x.w));
}

// Vb [b][s][h*64+d] bf16 -> Vt [bh][d][s] bf16
__global__ __launch_bounds__(256) void prep_v(const unsigned short* __restrict__ Vb,
                                              unsigned short* __restrict__ Vt)
{
    __shared__ unsigned Vl[64][34];
    const int k0 = blockIdx.x * 64;
    const int bh = blockIdx.y;
    const int b = bh >> 2, h = bh & 3;
    const int t = threadIdx.x;
    const unsigned* Vg = (const unsigned*)Vb + (size_t)(b * S_LEN) * 128 + h * 32;
    #pragma unroll
    for (int i = 0; i < 8; ++i) {
        int id = t + i * 256;
        int key = id >> 5, cu = id & 31;
        Vl[key][cu] = Vg[(size_t)(k0 + key) * 128 + cu];
    }
    __syncthreads();
    const unsigned short* Vl16 = (const unsigned short*)Vl;
    unsigned* Vo = (unsigned*)Vt + (size_t)bh * 65536;
    #pragma unroll
    for (int i = 0; i < 8; ++i) {
        int id = t + i * 256;
        int d = id >> 5, ku = id & 31;
        unsigned lo = Vl16[(2 * ku) * 68 + d];
        unsigned hi = Vl16[(2 * ku + 1) * 68 + d];
        Vo[(size_t)d * 1024 + (k0 >> 1) + ku] = lo | (hi << 16);
    }
}

// ---------------------------------------------------------------------------
// Global attention, split-K flash. grid (S/64, B*NH, 4 chunks), 256 thr.
// Each block: 64 q-rows x 512 keys (8 tiles). K/V reg-prefetch (T14).
// Partial outputs: Opart[ck][bh][s][64] fp32 (unnormalized), mlpart m,l.
// ---------------------------------------------------------------------------
__global__ __launch_bounds__(256) void attn_global_split(
    const unsigned short* __restrict__ Qb, const unsigned short* __restrict__ Kb,
    const unsigned short* __restrict__ Vt, const float* __restrict__ adj_w,
    const float* __restrict__ adj_b, float* __restrict__ Opart,
    float* __restrict__ mlpart)
{
    __shared__ unsigned Kl[2048];        // [key64][dh64] bf16, swizzled
    __shared__ unsigned Vl[2048];        // [dh64][key64] bf16, swizzled
    __shared__ unsigned Pl[4][512];      // per-wave [q16][key64] bf16, swizzled

    const int q0 = blockIdx.x * 64;
    const int bh = blockIdx.y;
    const int ck = blockIdx.z;
    const int b = bh >> 2, h = bh & 3;
    const int t = threadIdx.x;
    const int w = t >> 6, l = t & 63;
    const int lr = l & 15, lg = l >> 4;
    const float aw = adj_w[0], ab = adj_b[0];

    const int qrow = q0 + w * 16 + lr;
    const unsigned* qb32 = (const unsigned*)Qb + (size_t)(b * S_LEN + qrow) * 128 + h * 32;
    bf16x8 qf[2];
    #pragma unroll
    for (int hh = 0; hh < 2; ++hh) {
        union { unsigned u[4]; bf16x8 v; } tmpu;
        #pragma unroll
        for (int jj = 0; jj < 4; ++jj) tmpu.u[jj] = qb32[hh * 16 + lg * 4 + jj];
        qf[hh] = tmpu.v;
    }

    const unsigned* Kg = (const unsigned*)Kb + (size_t)(b * S_LEN) * 128 + h * 32;
    const unsigned* Vg = (const unsigned*)Vt + (size_t)bh * 65536;
    const int kbase = ck * 512;

    float mrow = -1e30f, lrow = 0.f;
    f32x4 o[4] = {};
    uint4 rk[2], rv[2];

    // prologue: load + write tile 0
    #pragma unroll
    for (int i = 0; i < 2; ++i) {
        int id4 = t + i * 256;
        int r4 = id4 >> 3, c4 = id4 & 7;
        rk[i] = *(const uint4*)(Kg + (size_t)(kbase + r4) * 128 + c4 * 4);
        rv[i] = *(const uint4*)(Vg + (size_t)r4 * 1024 + (kbase >> 1) + c4 * 4);
    }
    #pragma unroll
    for (int i = 0; i < 2; ++i) {
        int id4 = t + i * 256;
        int r4 = id4 >> 3, c4 = id4 & 7;
        *(uint4*)((char*)Kl + swz(r4 * 128 + c4 * 16)) = rk[i];
        *(uint4*)((char*)Vl + swz(r4 * 128 + c4 * 16)) = rv[i];
    }

    for (int tt = 0; tt < 8; ++tt) {
        const int k0 = kbase + tt * 64;
        __syncthreads();                         // tile tt staged for all waves
        if (tt < 7) {                            // prefetch tile tt+1 into regs
            const int kn = k0 + 64;
            #pragma unroll
            for (int i = 0; i < 2; ++i) {
                int id4 = t + i * 256;
                int r4 = id4 >> 3, c4 = id4 & 7;
                rk[i] = *(const uint4*)(Kg + (size_t)(kn + r4) * 128 + c4 * 4);
                rv[i] = *(const uint4*)(Vg + (size_t)r4 * 1024 + (kn >> 1) + c4 * 4);
            }
        }

        // S^T = K @ Q
        float sv[4][4];
        #pragma unroll
        for (int f = 0; f < 4; ++f) {
            int krow = f * 16 + lr;
            bf16x8 kf0 = *(const bf16x8*)((const char*)Kl + swz(krow * 128 + lg * 16));
            bf16x8 kf1 = *(const bf16x8*)((const char*)Kl + swz(krow * 128 + lg * 16 + 64));
            f32x4 stf = {0.f, 0.f, 0.f, 0.f};
            stf = __builtin_amdgcn_mfma_f32_16x16x32_bf16(kf0, qf[0], stf, 0, 0, 0);
            stf = __builtin_amdgcn_mfma_f32_16x16x32_bf16(kf1, qf[1], stf, 0, 0, 0);
            int klo = k0 + f * 16;
            bool near = (q0 + w * 16 + 15 >= klo - 6) && (q0 + w * 16 <= klo + 21);
            #pragma unroll
            for (int r = 0; r < 4; ++r) {
                float x = stf[r] * ATT_SCALE;
                if (near) {
                    int key = klo + lg * 4 + r;
                    float dd = (float)(qrow - key);
                    x += __expf(-fabsf(aw * dd * dd - ab));
                }
                sv[f][r] = x;
            }
        }

        // online softmax (per q-row across lanes lr, lr+16, lr+32, lr+48)
        float tmax = -1e30f;
        #pragma unroll
        for (int f = 0; f < 4; ++f)
            #pragma unroll
            for (int r = 0; r < 4; ++r) tmax = fmaxf(tmax, sv[f][r]);
        tmax = fmaxf(tmax, __shfl_xor(tmax, 16, 64));
        tmax = fmaxf(tmax, __shfl_xor(tmax, 32, 64));
        float mnew = fmaxf(mrow, tmax);
        float fac  = __expf(mrow - mnew);
        float ts = 0.f;
        #pragma unroll
        for (int f = 0; f < 4; ++f)
            #pragma unroll
            for (int r = 0; r < 4; ++r) {
                float p = __expf(sv[f][r] - mnew);
                sv[f][r] = p; ts += p;
            }
        ts += __shfl_xor(ts, 16, 64);
        ts += __shfl_xor(ts, 32, 64);
        lrow = lrow * fac + ts;
        mrow = mnew;
        #pragma unroll
        for (int rf = 0; rf < 4; ++rf) o[rf] *= fac;

        // pack P^T (wave-local LDS, no barrier needed)
        #pragma unroll
        for (int f = 0; f < 4; ++f) {
            uint2 pw;
            pw.x = packbf(sv[f][0], sv[f][1]);
            pw.y = packbf(sv[f][2], sv[f][3]);
            *(uint2*)((char*)Pl[w] + swz(lr * 128 + f * 32 + lg * 8)) = pw;
        }

        // O^T += V^T @ P^T
        #pragma unroll
        for (int hh = 0; hh < 2; ++hh) {
            bf16x8 pf = *(const bf16x8*)((const char*)Pl[w] + swz(lr * 128 + lg * 16 + 64 * hh));
            #pragma unroll
            for (int rf = 0; rf < 4; ++rf) {
                int vrow = rf * 16 + lr;
                bf16x8 vf = *(const bf16x8*)((const char*)Vl + swz(vrow * 128 + lg * 16 + 64 * hh));
                o[rf] = __builtin_amdgcn_mfma_f32_16x16x32_bf16(vf, pf, o[rf], 0, 0, 0);
            }
        }

        __syncthreads();                         // all waves done reading Kl/Vl
        if (tt < 7) {                            // write prefetched tile tt+1
            #pragma unroll
            for (int i = 0; i < 2; ++i) {
                int id4 = t + i * 256;
                int r4 = id4 >> 3, c4 = id4 & 7;
                *(uint4*)((char*)Kl + swz(r4 * 128 + c4 * 16)) = rk[i];
                *(uint4*)((char*)Vl + swz(r4 * 128 + c4 * 16)) = rv[i];
            }
        }
    }

    // write partials (unnormalized)
    const size_t idx = (size_t)(ck * 8 + bh) * 2048 + qrow;
    float* op = Opart + idx * 64;
    #pragma unroll
    for (int rf = 0; rf < 4; ++rf)
        *(float4*)(op + rf * 16 + lg * 4) = make_float4(o[rf][0], o[rf][1], o[rf][2], o[rf][3]);
    if (lg == 0) {
        mlpart[idx * 2]     = mrow;
        mlpart[idx * 2 + 1] = lrow;
    }
}

// ---------------------------------------------------------------------------
// Merge split-K partials + mix with local attention + signed sqrt -> tmpb bf16.
// grid = B*S blocks of 256 (wave w = head h, lane = dh).
// ---------------------------------------------------------------------------
__global__ __launch_bounds__(256) void attn_combine(
    const float* __restrict__ Opart, const float* __restrict__ mlpart,
    const unsigned short* __restrict__ lcl_b, const float* __restrict__ alpha,
    unsigned short* __restrict__ tmpb)
{
    const int row = blockIdx.x;            // b*2048 + s
    const int b = row >> 11;
    const int w = threadIdx.x >> 6;        // h
    const int lane = threadIdx.x & 63;     // dh
    const size_t base = (size_t)(b * NH + w) * 2048 + (row & 2047);

    float mv[4], lv[4];
    float M = -1e30f;
    #pragma unroll
    for (int ck = 0; ck < 4; ++ck) {
        mv[ck] = mlpart[(ck * 16384 + base) * 2];
        lv[ck] = mlpart[(ck * 16384 + base) * 2 + 1];
        M = fmaxf(M, mv[ck]);
    }
    float O = 0.f, L = 0.f;
    #pragma unroll
    for (int ck = 0; ck < 4; ++ck) {
        float e = __expf(mv[ck] - M);
        O += e * Opart[(ck * 16384 + base) * 64 + lane];
        L += e * lv[ck];
    }
    float g = O / L;
    float lval = bf2f(lcl_b[(size_t)row * HID + w * 64 + lane]);
    float a = 1.f / (1.f + expf(-alpha[0]));
    float x = a * g + (1.f - a) * lval;
    float r = x > 0.f ? sqrtf(x) : (x < 0.f ? -sqrtf(-x) : 0.f);
    tmpb[(size_t)row * HID + w * 64 + lane] = f2bf(r);
}

// ---------------------------------------------------------------------------
// Local windowed attention (WIN=9, clipped indices dedup'd), bf16 in/out.
// ---------------------------------------------------------------------------
__global__ __launch_bounds__(256) void attn_local(
    const unsigned short* __restrict__ Qb, const unsigned short* __restrict__ Kb,
    const unsigned short* __restrict__ Vb, const float* __restrict__ adj_w,
    const float* __restrict__ adj_b, unsigned short* __restrict__ lcl_b)
{
    const int wave = threadIdx.x >> 6;
    const int lane = threadIdx.x & 63;
    const int gr = blockIdx.x * 4 + wave;
    const int b = gr >> 13;
    const int rem = gr & 8191;
    const int h = rem >> 11;
    const int i = rem & 2047;
    const float w = adj_w[0], bb = adj_b[0];

    const float qd = bf2f(Qb[(size_t)(b * S_LEN + i) * HID + h * 64 + lane]);

    float sc[9]; int cls[9];
    float mx = -1e30f; int prev = -1;
    #pragma unroll
    for (int kk = 0; kk < 9; ++kk) {
        int c = i - 4 + kk;
        c = c < 0 ? 0 : (c > S_LEN - 1 ? S_LEN - 1 : c);
        bool valid = (c != prev);
        prev = c;
        float kd = bf2f(Kb[(size_t)(b * S_LEN + c) * HID + h * 64 + lane]);
        float part = qd * kd;
        #pragma unroll
        for (int off = 32; off; off >>= 1) part += __shfl_xor(part, off, 64);
        float dd = fabsf((float)(i - c));
        float vv = part * ATT_SCALE + expf(-fabsf(w * dd * dd - bb));
        sc[kk]  = valid ? vv : -1e30f;
        cls[kk] = c;
        mx = fmaxf(mx, sc[kk]);
    }
    float sum = 0.f;
    #pragma unroll
    for (int kk = 0; kk < 9; ++kk) { sc[kk] = expf(sc[kk] - mx); sum += sc[kk]; }
    const float inv = 1.f / sum;
    float o = 0.f;
    #pragma unroll
    for (int kk = 0; kk < 9; ++kk)
        o += sc[kk] * bf2f(Vb[(size_t)(b * S_LEN + cls[kk]) * HID + h * 64 + lane]);

    lcl_b[((size_t)(b * S_LEN + i)) * HID + h * 64 + lane] = f2bf(o * inv);
}

// ---------------------------------------------------------------------------
// partial column sums of squares: 256 blocks = (b, s-chunk of 16), 256 thr = c
__global__ __launch_bounds__(256) void colnorm_part(
    const unsigned short* __restrict__ tmpb, float* __restrict__ part)
{
    const int b = blockIdx.x >> 7, ch = blockIdx.x & 127;
    const int s0 = ch * 16;
    const unsigned short* base = tmpb + ((size_t)b * S_LEN + s0) * HID + threadIdx.x;
    float ss = 0.f;
    #pragma unroll
    for (int s = 0; s < 16; ++s) {
        float v2 = bf2f(base[(size_t)s * HID]);
        ss += v2 * v2;
    }
    part[blockIdx.x * 256 + threadIdx.x] = ss;
}

__global__ void colnorm_fin(const float* __restrict__ part, float* __restrict__ inv_nrm)
{
    const int tid = threadIdx.x;          // 512 = b*256+c
    const int b = tid >> 8, c = tid & 255;
    float s = 0.f;
    for (int ch = 0; ch < 128; ++ch) s += part[(b * 128 + ch) * 256 + c];
    inv_nrm[tid] = 1.f / fmaxf(sqrtf(s), 1e-12f);
}

__global__ __launch_bounds__(256) void scale_inv(
    unsigned short* __restrict__ tmpb, const float* __restrict__ inv_nrm)
{
    int idx = blockIdx.x * 256 + threadIdx.x;
    int c = idx & 255, b = idx >> 19;
    tmpb[idx] = f2bf(bf2f(tmpb[idx]) * inv_nrm[b * 256 + c]);
}

// ---------------------------------------------------------------------------
// LayerNorm over last dim (1024). Optional fp32 and/or bf16 outputs.
// ---------------------------------------------------------------------------
__global__ __launch_bounds__(256) void layernorm_k(
    const float* __restrict__ x, const float* __restrict__ g,
    const float* __restrict__ be, float* __restrict__ outf,
    unsigned short* __restrict__ outb)
{
    const int row = blockIdx.x;
    const float4 xv = ((const float4*)(x + (size_t)row * DMODEL))[threadIdx.x];
    float s  = xv.x + xv.y + xv.z + xv.w;
    float ss = xv.x * xv.x + xv.y * xv.y + xv.z * xv.z + xv.w * xv.w;
    #pragma unroll
    for (int off = 32; off; off >>= 1) {
        s  += __shfl_xor(s,  off, 64);
        ss += __shfl_xor(ss, off, 64);
    }
    __shared__ float rs[4], rss[4];
    if ((threadIdx.x & 63) == 0) { rs[threadIdx.x >> 6] = s; rss[threadIdx.x >> 6] = ss; }
    __syncthreads();
    s  = rs[0] + rs[1] + rs[2] + rs[3];
    ss = rss[0] + rss[1] + rss[2] + rss[3];
    const float mu  = s * (1.f / DMODEL);
    const float var = ss * (1.f / DMODEL) - mu * mu;
    const float r   = rsqrtf(var + LN_EPS);
    const float4 gv = ((const float4*)g)[threadIdx.x];
    const float4 bv = ((const float4*)be)[threadIdx.x];
    float4 ov;
    ov.x = (xv.x - mu) * r * gv.x + bv.x;
    ov.y = (xv.y - mu) * r * gv.y + bv.y;
    ov.z = (xv.z - mu) * r * gv.z + bv.z;
    ov.w = (xv.w - mu) * r * gv.w + bv.w;
    if (outf) ((float4*)(outf + (size_t)row * DMODEL))[threadIdx.x] = ov;
    if (outb) {
        unsigned* ob = (unsigned*)(outb + (size_t)row * DMODEL);
        ob[threadIdx.x * 2]     = packbf(ov.x, ov.y);
        ob[threadIdx.x * 2 + 1] = packbf(ov.z, ov.w);
    }
}

// ---------------------------------------------------------------------------
extern "C" void kernel_launch(void* const* d_in, const int* in_sizes, int n_in,
                              void* d_out, int out_size, void* d_ws, size_t ws_size,
                              hipStream_t stream)
{
    const float* q     = (const float*)d_in[0];
    const float* k     = (const float*)d_in[1];
    const float* v     = (const float*)d_in[2];
    const float* Wq    = (const float*)d_in[3];
    const float* bq    = (const float*)d_in[4];
    const float* Wk    = (const float*)d_in[5];
    const float* bk    = (const float*)d_in[6];
    const float* Wv    = (const float*)d_in[7];
    const float* bv    = (const float*)d_in[8];
    const float* Wo    = (const float*)d_in[9];
    const float* bo    = (const float*)d_in[10];
    const float* alpha = (const float*)d_in[11];
    const float* adj_w = (const float*)d_in[12];
    const float* adj_b = (const float*)d_in[13];
    const float* W1    = (const float*)d_in[14];
    const float* b1    = (const float*)d_in[15];
    const float* W2    = (const float*)d_in[16];
    const float* b2    = (const float*)d_in[17];
    const float* g1    = (const float*)d_in[18];
    const float* be1   = (const float*)d_in[19];
    const float* g2    = (const float*)d_in[20];
    const float* be2   = (const float*)d_in[21];

    const int ROWS = B_SZ * S_LEN;     // 4096

    // Workspace layout (bytes):
    // [0,16)   x1 fp32 / qkvb bf16 (first 16MB) / Opart fp32   (time-disjoint)
    // [16,24)  qkvb tail / mlpart / xlnb bf16                  (time-disjoint)
    // [26,28)  lcl_b     [28,30) Qb / hbufb   [30,32) Kb   [32,34) Vb
    // [34,36)  Vt        [36,38) tmpb
    // [38,39)  invn (2KB) + part (256KB)
    // [39,43)  Wt
    char* WS = (char*)d_ws;
    float*          x1     = (float*)WS;
    float*          Opart  = (float*)WS;                                 // 16MB
    unsigned short* qkvb   = (unsigned short*)WS;                        // 24MB
    float*          mlpart = (float*)(WS + (16u << 20));                 // 512KB
    unsigned short* xlnb   = (unsigned short*)(WS + (16u << 20));        // 8MB
    unsigned short* lcl_b  = (unsigned short*)(WS + (26u << 20));
    unsigned short* Qb     = (unsigned short*)(WS + (28u << 20));
    unsigned short* Kb     = (unsigned short*)(WS + (30u << 20));
    unsigned short* Vb     = (unsigned short*)(WS + (32u << 20));
    unsigned short* Vt     = (unsigned short*)(WS + (34u << 20));
    unsigned short* tmpb   = (unsigned short*)(WS + (36u << 20));
    float*          invn   = (float*)(WS + (38u << 20));
    float*          part   = (float*)(WS + (38u << 20) + 4096);
    unsigned short* Wt     = (unsigned short*)(WS + (39u << 20));
    unsigned short* hbufb  = (unsigned short*)(WS + (28u << 20));        // alias Qb/Kb

    // 1. weight transpose + bf16
    prep_w<<<dim3(512), dim3(256), 0, stream>>>(Wq, Wk, Wv, Wo, W1, W2, Wt);
    // 2. q,k,v -> bf16
    prep_qkv<<<dim3(4096, 1, 3), dim3(256), 0, stream>>>(q, k, v, qkvb);
    // 3. QKV projections -> Qb/Kb/Vb bf16
    gemm_qkv3<<<dim3(64, 4, 3), dim3(64), 0, stream>>>(qkvb, Wt, bq, bk, bv, Qb);
    // 4. V transpose
    prep_v<<<dim3(32, 8), dim3(256), 0, stream>>>(Vb, Vt);
    // 5. attention (split-K x4) + local
    attn_global_split<<<dim3(32, 8, 4), dim3(256), 0, stream>>>(Qb, Kb, Vt, adj_w, adj_b,
                                                                Opart, mlpart);
    attn_local<<<dim3(4096), dim3(256), 0, stream>>>(Qb, Kb, Vb, adj_w, adj_b, lcl_b);
    // 6. merge partials + mix + signed sqrt -> tmpb
    attn_combine<<<dim3(4096), dim3(256), 0, stream>>>(Opart, mlpart, lcl_b, alpha, tmpb);
    // 7. L2 norm over sequence axis
    colnorm_part<<<dim3(256), dim3(256), 0, stream>>>(tmpb, part);
    colnorm_fin<<<dim3(1), dim3(512), 0, stream>>>(part, invn);
    scale_inv<<<dim3(4096), dim3(256), 0, stream>>>(tmpb, invn);
    // 8. attn_out = tmpb @ Wo + bo + q -> x1 (fp32)
    gemm_b16<<<dim3(64, 16), dim3(64), 0, stream>>>(tmpb, Wt + 786432, bo, q, nullptr,
                                                    x1, nullptr, DMODEL, HID, 0);
    // 9. LN1 -> xlnb (bf16)
    layernorm_k<<<dim3(ROWS), dim3(256), 0, stream>>>(x1, g1, be1, nullptr, xlnb);
    // 10. FFN1 -> hbufb (bf16, relu)
    gemm_b16<<<dim3(64, 8), dim3(64), 0, stream>>>(xlnb, Wt + 1048576, b1, nullptr, nullptr,
                                                   nullptr, hbufb, DFF, DMODEL, 1);
    // 11. FFN2 + resid xlnb -> x1 (fp32)
    gemm_b16<<<dim3(64, 16), dim3(64), 0, stream>>>(hbufb, Wt + 1572864, b2, nullptr, xlnb,
                                                    x1, nullptr, DMODEL, DFF, 0);
    // 12. LN2 -> output
    layernorm_k<<<dim3(ROWS), dim3(256), 0, stream>>>(x1, g2, be2, (float*)d_out, nullptr);
}

// Round 6
// 268.297 us; speedup vs baseline: 1.4263x; 1.4263x over previous
//
#include <hip/hip_runtime.h>

// Problem constants
#define B_SZ   2
#define S_LEN  2048
#define DMODEL 1024
#define HID    256
#define NH     4
#define DH     64
#define DFF    512
#define LN_EPS 1e-5f
#define ATT_SCALE 0.0625f   // 1/sqrt(HID)

typedef __attribute__((ext_vector_type(8))) short bf16x8;
typedef __attribute__((ext_vector_type(4))) float f32x4;

// fp32 -> bf16 RNE
static __device__ __forceinline__ unsigned short f2bf(float x) {
    union { float f; unsigned u; } v; v.f = x;
    unsigned r = v.u + 0x7FFFu + ((v.u >> 16) & 1u);
    return (unsigned short)(r >> 16);
}
static __device__ __forceinline__ unsigned packbf(float a, float b) {
    return (unsigned)f2bf(a) | ((unsigned)f2bf(b) << 16);
}
static __device__ __forceinline__ float bf2f(unsigned short h) {
    union { unsigned u; float f; } v; v.u = ((unsigned)h) << 16; return v.f;
}
// LDS swizzle for 128B rows (byte bits 4-6 ^= bits 7-9), involution
static __device__ __forceinline__ int swz(int byte) {
    return byte ^ ((byte >> 3) & 0x70);
}

#if defined(__has_builtin)
#if __has_builtin(__builtin_amdgcn_global_load_lds)
#define HAVE_GLD 1
#endif
#endif

// async global->LDS, 16B per lane, LDS dest = wave-uniform base + lane*16
static __device__ __forceinline__ void gld16(const void* g, void* l) {
#ifdef HAVE_GLD
    __builtin_amdgcn_global_load_lds(
        (const __attribute__((address_space(1))) void*)g,
        (__attribute__((address_space(3))) void*)l, 16, 0, 0);
#else
    *(uint4*)((char*)l + (threadIdx.x & 63) * 16) = *(const uint4*)g;
#endif
}

// ---------------------------------------------------------------------------
// bf16 GEMM: 64x64 tile, 256 thr = 4 waves, BK=64, double-buffered
// global_load_lds staging (swizzled via pre-swizzled global source).
// Wave w computes a 64x16 column strip (acc = 4 x f32x4 = 16 VGPR).
// Epilogue: LDS transpose -> fully coalesced float4/uint2 stores.
// A [M][K] bf16 row-major, W [N][K] bf16 (pre-transposed weights).
// ---------------------------------------------------------------------------
__device__ __forceinline__ void stage_tile(const unsigned short* __restrict__ G,
                                           int row0, int k0, int K, char* lds, int t)
{
    // 8KB tile [64 rows][64 k] bf16; 256 threads x 2 gld16 calls
    #pragma unroll
    for (int i = 0; i < 2; ++i) {
        int ci = (t >> 6) * 2 + i;             // wave-uniform chunk 0..7
        int o  = (ci * 64 + (t & 63)) * 16;    // linear LDS byte offset
        int L  = o ^ ((o >> 3) & 0x70);        // logical (row,col) after swizzle
        const char* ga = (const char*)G +
            ((size_t)(row0 + (L >> 7)) * K + k0) * 2 + (L & 127);
        gld16(ga, lds + ci * 1024);
    }
}

__device__ __forceinline__ void compute_strip(const char* As, const char* Bs,
                                              f32x4 acc[4], int w, int lr, int lg)
{
    #pragma unroll
    for (int ks = 0; ks < 2; ++ks) {
        int koff = ks * 64 + lg * 16;
        bf16x8 bfv = *(const bf16x8*)(Bs + (((w * 16 + lr) * 128 + koff) ^ ((lr & 7) << 4)));
        #pragma unroll
        for (int m = 0; m < 4; ++m) {
            int r = m * 16 + lr;
            bf16x8 af = *(const bf16x8*)(As + ((r * 128 + koff) ^ ((lr & 7) << 4)));
            acc[m] = __builtin_amdgcn_mfma_f32_16x16x32_bf16(af, bfv, acc[m], 0, 0, 0);
        }
    }
}

__device__ __forceinline__ void gemm64_core(
    const unsigned short* __restrict__ A, const unsigned short* __restrict__ W,
    const float* __restrict__ bias, const float* __restrict__ residf,
    const unsigned short* __restrict__ residb,
    float* __restrict__ Cf, unsigned short* __restrict__ Cb,
    int N, int K, int relu, int row0, int col0)
{
    __shared__ char ldsb[32768];               // dbuf staging; reused as fp32 T
    char* As0 = ldsb;          char* Bs0 = ldsb + 8192;
    char* As1 = ldsb + 16384;  char* Bs1 = ldsb + 24576;

    const int t = threadIdx.x;
    const int w = t >> 6, l = t & 63;
    const int lr = l & 15, lg = l >> 4;

    f32x4 acc[4] = {};

    stage_tile(A, row0, 0, K, As0, t);
    stage_tile(W, col0, 0, K, Bs0, t);
    __syncthreads();                            // drains gld (vmcnt0)

    const int NK = K >> 6;
    int buf = 0;
    for (int ks = 0; ks < NK; ++ks) {
        if (ks + 1 < NK) {                      // issue next tile (async)
            stage_tile(A, row0, (ks + 1) * 64, K, buf ? As0 : As1, t);
            stage_tile(W, col0, (ks + 1) * 64, K, buf ? Bs0 : Bs1, t);
        }
        compute_strip(buf ? As1 : As0, buf ? Bs1 : Bs0, acc, w, lr, lg);
        __syncthreads();                        // reads done + next staged
        buf ^= 1;
    }

    // epilogue: transpose through LDS -> coalesced stores
    float* T = (float*)ldsb;                    // [64][65] fp32
    #pragma unroll
    for (int m = 0; m < 4; ++m)
        #pragma unroll
        for (int r = 0; r < 4; ++r)
            T[(m * 16 + lg * 4 + r) * 65 + w * 16 + lr] =
                acc[m][r] + bias[col0 + w * 16 + lr];
    __syncthreads();

    #pragma unroll
    for (int i = 0; i < 4; ++i) {
        int idx = t + i * 256;
        int row = idx >> 4, c4 = idx & 15;
        float v0 = T[row * 65 + c4 * 4 + 0];
        float v1 = T[row * 65 + c4 * 4 + 1];
        float v2 = T[row * 65 + c4 * 4 + 2];
        float v3 = T[row * 65 + c4 * 4 + 3];
        size_t goff = (size_t)(row0 + row) * N + col0 + c4 * 4;
        if (residf) {
            float4 rv = *(const float4*)(residf + goff);
            v0 += rv.x; v1 += rv.y; v2 += rv.z; v3 += rv.w;
        }
        if (residb) {
            uint2 rb = *(const uint2*)(residb + goff);
            v0 += bf2f((unsigned short)(rb.x & 0xFFFF));
            v1 += bf2f((unsigned short)(rb.x >> 16));
            v2 += bf2f((unsigned short)(rb.y & 0xFFFF));
            v3 += bf2f((unsigned short)(rb.y >> 16));
        }
        if (relu) {
            v0 = fmaxf(v0, 0.f); v1 = fmaxf(v1, 0.f);
            v2 = fmaxf(v2, 0.f); v3 = fmaxf(v3, 0.f);
        }
        if (Cb) *(uint2*)(Cb + goff) = make_uint2(packbf(v0, v1), packbf(v2, v3));
        else    *(float4*)(Cf + goff) = make_float4(v0, v1, v2, v3);
    }
}

__global__ __launch_bounds__(256) void gemm_b16(
    const unsigned short* __restrict__ A, const unsigned short* __restrict__ W,
    const float* __restrict__ bias, const float* __restrict__ residf,
    const unsigned short* __restrict__ residb,
    float* __restrict__ Cf, unsigned short* __restrict__ Cb,
    int N, int K, int relu)
{
    gemm64_core(A, W, bias, residf, residb, Cf, Cb, N, K, relu,
                blockIdx.x * 64, blockIdx.y * 64);
}

__global__ __launch_bounds__(256) void gemm_qkv3(
    const unsigned short* __restrict__ qkvb, const unsigned short* __restrict__ Wt,
    const float* __restrict__ bq, const float* __restrict__ bk,
    const float* __restrict__ bv, unsigned short* __restrict__ outb)
{
    const int z = blockIdx.z;
    const unsigned short* A = qkvb + (size_t)z * 4096 * 1024;
    const unsigned short* W = Wt + (size_t)z * 262144;
    const float* bias = (z == 0) ? bq : ((z == 1) ? bk : bv);
    unsigned short* Cb = outb + (size_t)z * 4096 * 256;
    gemm64_core(A, W, bias, nullptr, nullptr, nullptr, Cb, 256, 1024, 0,
                blockIdx.x * 64, blockIdx.y * 64);
}

// ---------------------------------------------------------------------------
// Weight prep: fp32 [K][N] -> bf16 [N][K], all 6 weights in one launch.
// ---------------------------------------------------------------------------
__global__ __launch_bounds__(256) void prep_w(
    const float* __restrict__ Wq, const float* __restrict__ Wk,
    const float* __restrict__ Wv, const float* __restrict__ Wo,
    const float* __restrict__ W1, const float* __restrict__ W2,
    unsigned short* __restrict__ Wt)
{
    __shared__ float tile[64][65];
    const int bid = blockIdx.x;
    const float* src; int K, N; size_t off; int local;
    if (bid < 64)       { src = Wq; K = 1024; N = 256;  off = 0;        local = bid; }
    else if (bid < 128) { src = Wk; K = 1024; N = 256;  off = 262144;  local = bid - 64; }
    else if (bid < 192) { src = Wv; K = 1024; N = 256;  off = 524288;  local = bid - 128; }
    else if (bid < 256) { src = Wo; K = 256;  N = 1024; off = 786432;  local = bid - 192; }
    else if (bid < 384) { src = W1; K = 1024; N = 512;  off = 1048576; local = bid - 256; }
    else                { src = W2; K = 512;  N = 1024; off = 1572864; local = bid - 384; }
    const int nkt = K >> 6;
    const int k0 = (local % nkt) * 64, n0 = (local / nkt) * 64;
    const int t = threadIdx.x;
    #pragma unroll
    for (int i = 0; i < 16; ++i) {
        int id = t + i * 256;
        int r = id >> 6, c = id & 63;
        tile[r][c] = src[(size_t)(k0 + r) * N + n0 + c];
    }
    __syncthreads();
    unsigned* Wt32 = (unsigned*)(Wt + off);
    #pragma unroll
    for (int i = 0; i < 8; ++i) {
        int id = t + i * 256;
        int n = id >> 5, ku = id & 31;
        Wt32[((size_t)(n0 + n) * K + k0) / 2 + ku] =
            packbf(tile[2 * ku][n], tile[2 * ku + 1][n]);
    }
}

// q,k,v fp32 -> bf16 contiguous [3][4096][1024]
__global__ __launch_bounds__(256) void prep_qkv(
    const float* __restrict__ q, const float* __restrict__ k,
    const float* __restrict__ v, unsigned short* __restrict__ qkvb)
{
    const float* src = blockIdx.z == 0 ? q : (blockIdx.z == 1 ? k : v);
    uint2* dst = (uint2*)(qkvb + (size_t)blockIdx.z * 4096 * 1024);
    int idx = blockIdx.x * 256 + threadIdx.x;
    float4 x = ((const float4*)src)[idx];
    dst[idx] = make_uint2(packbf(x.x, x.y), packbf(x.z, x.w));
}

// Vb [b][s][h*64+d] bf16 -> Vt [bh][d][s] bf16
__global__ __launch_bounds__(256) void prep_v(const unsigned short* __restrict__ Vb,
                                              unsigned short* __restrict__ Vt)
{
    __shared__ unsigned Vl[64][34];
    const int k0 = blockIdx.x * 64;
    const int bh = blockIdx.y;
    const int b = bh >> 2, h = bh & 3;
    const int t = threadIdx.x;
    const unsigned* Vg = (const unsigned*)Vb + (size_t)(b * S_LEN) * 128 + h * 32;
    #pragma unroll
    for (int i = 0; i < 8; ++i) {
        int id = t + i * 256;
        int key = id >> 5, cu = id & 31;
        Vl[key][cu] = Vg[(size_t)(k0 + key) * 128 + cu];
    }
    __syncthreads();
    const unsigned short* Vl16 = (const unsigned short*)Vl;
    unsigned* Vo = (unsigned*)Vt + (size_t)bh * 65536;
    #pragma unroll
    for (int i = 0; i < 8; ++i) {
        int id = t + i * 256;
        int d = id >> 5, ku = id & 31;
        unsigned lo = Vl16[(2 * ku) * 68 + d];
        unsigned hi = Vl16[(2 * ku + 1) * 68 + d];
        Vo[(size_t)d * 1024 + (k0 >> 1) + ku] = lo | (hi << 16);
    }
}

// ---------------------------------------------------------------------------
// Global attention, split-K flash. grid (S/64, B*NH, 4 chunks), 256 thr.
// Each block: 64 q-rows x 512 keys (8 tiles). K/V reg-prefetch (T14).
// ---------------------------------------------------------------------------
__global__ __launch_bounds__(256) void attn_global_split(
    const unsigned short* __restrict__ Qb, const unsigned short* __restrict__ Kb,
    const unsigned short* __restrict__ Vt, const float* __restrict__ adj_w,
    const float* __restrict__ adj_b, float* __restrict__ Opart,
    float* __restrict__ mlpart)
{
    __shared__ unsigned Kl[2048];        // [key64][dh64] bf16, swizzled
    __shared__ unsigned Vl[2048];        // [dh64][key64] bf16, swizzled
    __shared__ unsigned Pl[4][512];      // per-wave [q16][key64] bf16, swizzled

    const int q0 = blockIdx.x * 64;
    const int bh = blockIdx.y;
    const int ck = blockIdx.z;
    const int b = bh >> 2, h = bh & 3;
    const int t = threadIdx.x;
    const int w = t >> 6, l = t & 63;
    const int lr = l & 15, lg = l >> 4;
    const float aw = adj_w[0], ab = adj_b[0];

    const int qrow = q0 + w * 16 + lr;
    const unsigned* qb32 = (const unsigned*)Qb + (size_t)(b * S_LEN + qrow) * 128 + h * 32;
    bf16x8 qf[2];
    #pragma unroll
    for (int hh = 0; hh < 2; ++hh) {
        union { unsigned u[4]; bf16x8 v; } tmpu;
        #pragma unroll
        for (int jj = 0; jj < 4; ++jj) tmpu.u[jj] = qb32[hh * 16 + lg * 4 + jj];
        qf[hh] = tmpu.v;
    }

    const unsigned* Kg = (const unsigned*)Kb + (size_t)(b * S_LEN) * 128 + h * 32;
    const unsigned* Vg = (const unsigned*)Vt + (size_t)bh * 65536;
    const int kbase = ck * 512;

    float mrow = -1e30f, lrow = 0.f;
    f32x4 o[4] = {};
    uint4 rk[2], rv[2];

    #pragma unroll
    for (int i = 0; i < 2; ++i) {
        int id4 = t + i * 256;
        int r4 = id4 >> 3, c4 = id4 & 7;
        rk[i] = *(const uint4*)(Kg + (size_t)(kbase + r4) * 128 + c4 * 4);
        rv[i] = *(const uint4*)(Vg + (size_t)r4 * 1024 + (kbase >> 1) + c4 * 4);
    }
    #pragma unroll
    for (int i = 0; i < 2; ++i) {
        int id4 = t + i * 256;
        int r4 = id4 >> 3, c4 = id4 & 7;
        *(uint4*)((char*)Kl + swz(r4 * 128 + c4 * 16)) = rk[i];
        *(uint4*)((char*)Vl + swz(r4 * 128 + c4 * 16)) = rv[i];
    }

    for (int tt = 0; tt < 8; ++tt) {
        const int k0 = kbase + tt * 64;
        __syncthreads();
        if (tt < 7) {
            const int kn = k0 + 64;
            #pragma unroll
            for (int i = 0; i < 2; ++i) {
                int id4 = t + i * 256;
                int r4 = id4 >> 3, c4 = id4 & 7;
                rk[i] = *(const uint4*)(Kg + (size_t)(kn + r4) * 128 + c4 * 4);
                rv[i] = *(const uint4*)(Vg + (size_t)r4 * 1024 + (kn >> 1) + c4 * 4);
            }
        }

        float sv[4][4];
        #pragma unroll
        for (int f = 0; f < 4; ++f) {
            int krow = f * 16 + lr;
            bf16x8 kf0 = *(const bf16x8*)((const char*)Kl + swz(krow * 128 + lg * 16));
            bf16x8 kf1 = *(const bf16x8*)((const char*)Kl + swz(krow * 128 + lg * 16 + 64));
            f32x4 stf = {0.f, 0.f, 0.f, 0.f};
            stf = __builtin_amdgcn_mfma_f32_16x16x32_bf16(kf0, qf[0], stf, 0, 0, 0);
            stf = __builtin_amdgcn_mfma_f32_16x16x32_bf16(kf1, qf[1], stf, 0, 0, 0);
            int klo = k0 + f * 16;
            bool near = (q0 + w * 16 + 15 >= klo - 6) && (q0 + w * 16 <= klo + 21);
            #pragma unroll
            for (int r = 0; r < 4; ++r) {
                float x = stf[r] * ATT_SCALE;
                if (near) {
                    int key = klo + lg * 4 + r;
                    float dd = (float)(qrow - key);
                    x += __expf(-fabsf(aw * dd * dd - ab));
                }
                sv[f][r] = x;
            }
        }

        float tmax = -1e30f;
        #pragma unroll
        for (int f = 0; f < 4; ++f)
            #pragma unroll
            for (int r = 0; r < 4; ++r) tmax = fmaxf(tmax, sv[f][r]);
        tmax = fmaxf(tmax, __shfl_xor(tmax, 16, 64));
        tmax = fmaxf(tmax, __shfl_xor(tmax, 32, 64));
        float mnew = fmaxf(mrow, tmax);
        float fac  = __expf(mrow - mnew);
        float ts = 0.f;
        #pragma unroll
        for (int f = 0; f < 4; ++f)
            #pragma unroll
            for (int r = 0; r < 4; ++r) {
                float p = __expf(sv[f][r] - mnew);
                sv[f][r] = p; ts += p;
            }
        ts += __shfl_xor(ts, 16, 64);
        ts += __shfl_xor(ts, 32, 64);
        lrow = lrow * fac + ts;
        mrow = mnew;
        #pragma unroll
        for (int rf = 0; rf < 4; ++rf) o[rf] *= fac;

        #pragma unroll
        for (int f = 0; f < 4; ++f) {
            uint2 pw;
            pw.x = packbf(sv[f][0], sv[f][1]);
            pw.y = packbf(sv[f][2], sv[f][3]);
            *(uint2*)((char*)Pl[w] + swz(lr * 128 + f * 32 + lg * 8)) = pw;
        }

        #pragma unroll
        for (int hh = 0; hh < 2; ++hh) {
            bf16x8 pf = *(const bf16x8*)((const char*)Pl[w] + swz(lr * 128 + lg * 16 + 64 * hh));
            #pragma unroll
            for (int rf = 0; rf < 4; ++rf) {
                int vrow = rf * 16 + lr;
                bf16x8 vf = *(const bf16x8*)((const char*)Vl + swz(vrow * 128 + lg * 16 + 64 * hh));
                o[rf] = __builtin_amdgcn_mfma_f32_16x16x32_bf16(vf, pf, o[rf], 0, 0, 0);
            }
        }

        __syncthreads();
        if (tt < 7) {
            #pragma unroll
            for (int i = 0; i < 2; ++i) {
                int id4 = t + i * 256;
                int r4 = id4 >> 3, c4 = id4 & 7;
                *(uint4*)((char*)Kl + swz(r4 * 128 + c4 * 16)) = rk[i];
                *(uint4*)((char*)Vl + swz(r4 * 128 + c4 * 16)) = rv[i];
            }
        }
    }

    const size_t idx = (size_t)(ck * 8 + bh) * 2048 + qrow;
    float* op = Opart + idx * 64;
    #pragma unroll
    for (int rf = 0; rf < 4; ++rf)
        *(float4*)(op + rf * 16 + lg * 4) = make_float4(o[rf][0], o[rf][1], o[rf][2], o[rf][3]);
    if (lg == 0) {
        mlpart[idx * 2]     = mrow;
        mlpart[idx * 2 + 1] = lrow;
    }
}

// ---------------------------------------------------------------------------
// Merge split-K partials + mix with local attention + signed sqrt -> tmpb bf16.
// ---------------------------------------------------------------------------
__global__ __launch_bounds__(256) void attn_combine(
    const float* __restrict__ Opart, const float* __restrict__ mlpart,
    const unsigned short* __restrict__ lcl_b, const float* __restrict__ alpha,
    unsigned short* __restrict__ tmpb)
{
    const int row = blockIdx.x;            // b*2048 + s
    const int b = row >> 11;
    const int w = threadIdx.x >> 6;        // h
    const int lane = threadIdx.x & 63;     // dh
    const size_t base = (size_t)(b * NH + w) * 2048 + (row & 2047);

    float mv[4], lv[4];
    float M = -1e30f;
    #pragma unroll
    for (int ck = 0; ck < 4; ++ck) {
        mv[ck] = mlpart[(ck * 16384 + base) * 2];
        lv[ck] = mlpart[(ck * 16384 + base) * 2 + 1];
        M = fmaxf(M, mv[ck]);
    }
    float O = 0.f, L = 0.f;
    #pragma unroll
    for (int ck = 0; ck < 4; ++ck) {
        float e = __expf(mv[ck] - M);
        O += e * Opart[(ck * 16384 + base) * 64 + lane];
        L += e * lv[ck];
    }
    float g = O / L;
    float lval = bf2f(lcl_b[(size_t)row * HID + w * 64 + lane]);
    float a = 1.f / (1.f + expf(-alpha[0]));
    float x = a * g + (1.f - a) * lval;
    float r = x > 0.f ? sqrtf(x) : (x < 0.f ? -sqrtf(-x) : 0.f);
    tmpb[(size_t)row * HID + w * 64 + lane] = f2bf(r);
}

// ---------------------------------------------------------------------------
// Local windowed attention (WIN=9, clipped indices dedup'd), bf16 in/out.
// ---------------------------------------------------------------------------
__global__ __launch_bounds__(256) void attn_local(
    const unsigned short* __restrict__ Qb, const unsigned short* __restrict__ Kb,
    const unsigned short* __restrict__ Vb, const float* __restrict__ adj_w,
    const float* __restrict__ adj_b, unsigned short* __restrict__ lcl_b)
{
    const int wave = threadIdx.x >> 6;
    const int lane = threadIdx.x & 63;
    const int gr = blockIdx.x * 4 + wave;
    const int b = gr >> 13;
    const int rem = gr & 8191;
    const int h = rem >> 11;
    const int i = rem & 2047;
    const float w = adj_w[0], bb = adj_b[0];

    const float qd = bf2f(Qb[(size_t)(b * S_LEN + i) * HID + h * 64 + lane]);

    float sc[9]; int cls[9];
    float mx = -1e30f; int prev = -1;
    #pragma unroll
    for (int kk = 0; kk < 9; ++kk) {
        int c = i - 4 + kk;
        c = c < 0 ? 0 : (c > S_LEN - 1 ? S_LEN - 1 : c);
        bool valid = (c != prev);
        prev = c;
        float kd = bf2f(Kb[(size_t)(b * S_LEN + c) * HID + h * 64 + lane]);
        float part = qd * kd;
        #pragma unroll
        for (int off = 32; off; off >>= 1) part += __shfl_xor(part, off, 64);
        float dd = fabsf((float)(i - c));
        float vv = part * ATT_SCALE + expf(-fabsf(w * dd * dd - bb));
        sc[kk]  = valid ? vv : -1e30f;
        cls[kk] = c;
        mx = fmaxf(mx, sc[kk]);
    }
    float sum = 0.f;
    #pragma unroll
    for (int kk = 0; kk < 9; ++kk) { sc[kk] = expf(sc[kk] - mx); sum += sc[kk]; }
    const float inv = 1.f / sum;
    float o = 0.f;
    #pragma unroll
    for (int kk = 0; kk < 9; ++kk)
        o += sc[kk] * bf2f(Vb[(size_t)(b * S_LEN + cls[kk]) * HID + h * 64 + lane]);

    lcl_b[((size_t)(b * S_LEN + i)) * HID + h * 64 + lane] = f2bf(o * inv);
}

// ---------------------------------------------------------------------------
// partial column sums of squares: 256 blocks = (b, s-chunk of 16), LDS-staged.
__global__ __launch_bounds__(256) void colnorm_part(
    const unsigned short* __restrict__ tmpb, float* __restrict__ part)
{
    __shared__ unsigned short Tl[16][256];
    const int b = blockIdx.x >> 7, ch = blockIdx.x & 127;
    const int t = threadIdx.x;
    const uint4* src = (const uint4*)(tmpb + ((size_t)b * S_LEN + ch * 16) * HID);
    #pragma unroll
    for (int i = 0; i < 2; ++i) {
        int idx = t + i * 256;
        ((uint4*)Tl)[idx] = src[idx];
    }
    __syncthreads();
    float ss = 0.f;
    #pragma unroll
    for (int r = 0; r < 16; ++r) {
        float v2 = bf2f(Tl[r][t]);
        ss += v2 * v2;
    }
    part[blockIdx.x * 256 + t] = ss;
}

// 512 blocks (b*256+c) x 64 threads: wave-reduce 128 partials each
__global__ __launch_bounds__(64) void colnorm_fin(
    const float* __restrict__ part, float* __restrict__ inv_nrm)
{
    const int bc = blockIdx.x;
    const int b = bc >> 8, c = bc & 255;
    const int j = threadIdx.x;
    float s = part[(b * 128 + j) * 256 + c] + part[(b * 128 + j + 64) * 256 + c];
    #pragma unroll
    for (int off = 32; off; off >>= 1) s += __shfl_xor(s, off, 64);
    if (j == 0) inv_nrm[bc] = 1.f / fmaxf(sqrtf(s), 1e-12f);
}

__global__ __launch_bounds__(256) void scale_inv(
    unsigned short* __restrict__ tmpb, const float* __restrict__ inv_nrm)
{
    int idx = blockIdx.x * 256 + threadIdx.x;
    int c = idx & 255, b = idx >> 19;
    tmpb[idx] = f2bf(bf2f(tmpb[idx]) * inv_nrm[b * 256 + c]);
}

// ---------------------------------------------------------------------------
// LayerNorm over last dim (1024). Optional fp32 and/or bf16 outputs.
// ---------------------------------------------------------------------------
__global__ __launch_bounds__(256) void layernorm_k(
    const float* __restrict__ x, const float* __restrict__ g,
    const float* __restrict__ be, float* __restrict__ outf,
    unsigned short* __restrict__ outb)
{
    const int row = blockIdx.x;
    const float4 xv = ((const float4*)(x + (size_t)row * DMODEL))[threadIdx.x];
    float s  = xv.x + xv.y + xv.z + xv.w;
    float ss = xv.x * xv.x + xv.y * xv.y + xv.z * xv.z + xv.w * xv.w;
    #pragma unroll
    for (int off = 32; off; off >>= 1) {
        s  += __shfl_xor(s,  off, 64);
        ss += __shfl_xor(ss, off, 64);
    }
    __shared__ float rs[4], rss[4];
    if ((threadIdx.x & 63) == 0) { rs[threadIdx.x >> 6] = s; rss[threadIdx.x >> 6] = ss; }
    __syncthreads();
    s  = rs[0] + rs[1] + rs[2] + rs[3];
    ss = rss[0] + rss[1] + rss[2] + rss[3];
    const float mu  = s * (1.f / DMODEL);
    const float var = ss * (1.f / DMODEL) - mu * mu;
    const float r   = rsqrtf(var + LN_EPS);
    const float4 gv = ((const float4*)g)[threadIdx.x];
    const float4 bv = ((const float4*)be)[threadIdx.x];
    float4 ov;
    ov.x = (xv.x - mu) * r * gv.x + bv.x;
    ov.y = (xv.y - mu) * r * gv.y + bv.y;
    ov.z = (xv.z - mu) * r * gv.z + bv.z;
    ov.w = (xv.w - mu) * r * gv.w + bv.w;
    if (outf) ((float4*)(outf + (size_t)row * DMODEL))[threadIdx.x] = ov;
    if (outb) {
        unsigned* ob = (unsigned*)(outb + (size_t)row * DMODEL);
        ob[threadIdx.x * 2]     = packbf(ov.x, ov.y);
        ob[threadIdx.x * 2 + 1] = packbf(ov.z, ov.w);
    }
}

// ---------------------------------------------------------------------------
extern "C" void kernel_launch(void* const* d_in, const int* in_sizes, int n_in,
                              void* d_out, int out_size, void* d_ws, size_t ws_size,
                              hipStream_t stream)
{
    const float* q     = (const float*)d_in[0];
    const float* k     = (const float*)d_in[1];
    const float* v     = (const float*)d_in[2];
    const float* Wq    = (const float*)d_in[3];
    const float* bq    = (const float*)d_in[4];
    const float* Wk    = (const float*)d_in[5];
    const float* bk    = (const float*)d_in[6];
    const float* Wv    = (const float*)d_in[7];
    const float* bv    = (const float*)d_in[8];
    const float* Wo    = (const float*)d_in[9];
    const float* bo    = (const float*)d_in[10];
    const float* alpha = (const float*)d_in[11];
    const float* adj_w = (const float*)d_in[12];
    const float* adj_b = (const float*)d_in[13];
    const float* W1    = (const float*)d_in[14];
    const float* b1    = (const float*)d_in[15];
    const float* W2    = (const float*)d_in[16];
    const float* b2    = (const float*)d_in[17];
    const float* g1    = (const float*)d_in[18];
    const float* be1   = (const float*)d_in[19];
    const float* g2    = (const float*)d_in[20];
    const float* be2   = (const float*)d_in[21];

    const int ROWS = B_SZ * S_LEN;     // 4096

    // Workspace layout (bytes):
    char* WS = (char*)d_ws;
    float*          x1     = (float*)WS;
    float*          Opart  = (float*)WS;                                 // 16MB
    unsigned short* qkvb   = (unsigned short*)WS;                        // 24MB
    float*          mlpart = (float*)(WS + (16u << 20));                 // 512KB
    unsigned short* xlnb   = (unsigned short*)(WS + (16u << 20));        // 8MB
    unsigned short* lcl_b  = (unsigned short*)(WS + (26u << 20));
    unsigned short* Qb     = (unsigned short*)(WS + (28u << 20));
    unsigned short* Kb     = (unsigned short*)(WS + (30u << 20));
    unsigned short* Vb     = (unsigned short*)(WS + (32u << 20));
    unsigned short* Vt     = (unsigned short*)(WS + (34u << 20));
    unsigned short* tmpb   = (unsigned short*)(WS + (36u << 20));
    float*          invn   = (float*)(WS + (38u << 20));
    float*          part   = (float*)(WS + (38u << 20) + 4096);
    unsigned short* Wt     = (unsigned short*)(WS + (39u << 20));
    unsigned short* hbufb  = (unsigned short*)(WS + (28u << 20));        // alias Qb/Kb

    // 1. weight transpose + bf16
    prep_w<<<dim3(512), dim3(256), 0, stream>>>(Wq, Wk, Wv, Wo, W1, W2, Wt);
    // 2. q,k,v -> bf16
    prep_qkv<<<dim3(4096, 1, 3), dim3(256), 0, stream>>>(q, k, v, qkvb);
    // 3. QKV projections -> Qb/Kb/Vb bf16
    gemm_qkv3<<<dim3(64, 4, 3), dim3(256), 0, stream>>>(qkvb, Wt, bq, bk, bv, Qb);
    // 4. V transpose
    prep_v<<<dim3(32, 8), dim3(256), 0, stream>>>(Vb, Vt);
    // 5. attention (split-K x4) + local
    attn_global_split<<<dim3(32, 8, 4), dim3(256), 0, stream>>>(Qb, Kb, Vt, adj_w, adj_b,
                                                                Opart, mlpart);
    attn_local<<<dim3(4096), dim3(256), 0, stream>>>(Qb, Kb, Vb, adj_w, adj_b, lcl_b);
    // 6. merge partials + mix + signed sqrt -> tmpb
    attn_combine<<<dim3(4096), dim3(256), 0, stream>>>(Opart, mlpart, lcl_b, alpha, tmpb);
    // 7. L2 norm over sequence axis
    colnorm_part<<<dim3(256), dim3(256), 0, stream>>>(tmpb, part);
    colnorm_fin<<<dim3(512), dim3(64), 0, stream>>>(part, invn);
    scale_inv<<<dim3(4096), dim3(256), 0, stream>>>(tmpb, invn);
    // 8. attn_out = tmpb @ Wo + bo + q -> x1 (fp32)
    gemm_b16<<<dim3(64, 16), dim3(256), 0, stream>>>(tmpb, Wt + 786432, bo, q, nullptr,
                                                     x1, nullptr, DMODEL, HID, 0);
    // 9. LN1 -> xlnb (bf16)
    layernorm_k<<<dim3(ROWS), dim3(256), 0, stream>>>(x1, g1, be1, nullptr, xlnb);
    // 10. FFN1 -> hbufb (bf16, relu)
    gemm_b16<<<dim3(64, 8), dim3(256), 0, stream>>>(xlnb, Wt + 1048576, b1, nullptr, nullptr,
                                                    nullptr, hbufb, DFF, DMODEL, 1);
    // 11. FFN2 + resid xlnb -> x1 (fp32)
    gemm_b16<<<dim3(64, 16), dim3(256), 0, stream>>>(hbufb, Wt + 1572864, b2, nullptr, xlnb,
                                                     x1, nullptr, DMODEL, DFF, 0);
    // 12. LN2 -> output
    layernorm_k<<<dim3(ROWS), dim3(256), 0, stream>>>(x1, g2, be2, (float*)d_out, nullptr);
}

// Round 7
// 261.683 us; speedup vs baseline: 1.4623x; 1.0253x over previous
//
#include <hip/hip_runtime.h>

// Problem constants
#define B_SZ   2
#define S_LEN  2048
#define DMODEL 1024
#define HID    256
#define NH     4
#define DH     64
#define DFF    512
#define LN_EPS 1e-5f
#define ATT_SCALE 0.0625f   // 1/sqrt(HID)

typedef __attribute__((ext_vector_type(8))) short bf16x8;
typedef __attribute__((ext_vector_type(4))) float f32x4;

// fp32 -> bf16 RNE
static __device__ __forceinline__ unsigned short f2bf(float x) {
    union { float f; unsigned u; } v; v.f = x;
    unsigned r = v.u + 0x7FFFu + ((v.u >> 16) & 1u);
    return (unsigned short)(r >> 16);
}
static __device__ __forceinline__ unsigned packbf(float a, float b) {
    return (unsigned)f2bf(a) | ((unsigned)f2bf(b) << 16);
}
static __device__ __forceinline__ float bf2f(unsigned short h) {
    union { unsigned u; float f; } v; v.u = ((unsigned)h) << 16; return v.f;
}
// LDS swizzle for 128B rows (byte bits 4-6 ^= bits 7-9), involution
static __device__ __forceinline__ int swz(int byte) {
    return byte ^ ((byte >> 3) & 0x70);
}

#if defined(__has_builtin)
#if __has_builtin(__builtin_amdgcn_global_load_lds)
#define HAVE_GLD 1
#endif
#endif

// async global->LDS, 16B per lane, LDS dest = wave-uniform base + lane*16
static __device__ __forceinline__ void gld16(const void* g, void* l) {
#ifdef HAVE_GLD
    __builtin_amdgcn_global_load_lds(
        (const __attribute__((address_space(1))) void*)g,
        (__attribute__((address_space(3))) void*)l, 16, 0, 0);
#else
    *(uint4*)((char*)l + (threadIdx.x & 63) * 16) = *(const uint4*)g;
#endif
}

// ---------------------------------------------------------------------------
// bf16 GEMM: 64x64 tile, 256 thr = 4 waves, BK=64, double-buffered
// global_load_lds staging (swizzled via pre-swizzled global source).
// Wave w computes a 64x16 column strip. Epilogue: LDS transpose ->
// fully coalesced float4/uint2 stores.
// ---------------------------------------------------------------------------
__device__ __forceinline__ void stage_tile(const unsigned short* __restrict__ G,
                                           int row0, int k0, int K, char* lds, int t)
{
    #pragma unroll
    for (int i = 0; i < 2; ++i) {
        int ci = (t >> 6) * 2 + i;             // wave-uniform chunk 0..7
        int o  = (ci * 64 + (t & 63)) * 16;    // linear LDS byte offset
        int L  = o ^ ((o >> 3) & 0x70);        // logical (row,col) after swizzle
        const char* ga = (const char*)G +
            ((size_t)(row0 + (L >> 7)) * K + k0) * 2 + (L & 127);
        gld16(ga, lds + ci * 1024);
    }
}

__device__ __forceinline__ void compute_strip(const char* As, const char* Bs,
                                              f32x4 acc[4], int w, int lr, int lg)
{
    #pragma unroll
    for (int ks = 0; ks < 2; ++ks) {
        int koff = ks * 64 + lg * 16;
        bf16x8 bfv = *(const bf16x8*)(Bs + (((w * 16 + lr) * 128 + koff) ^ ((lr & 7) << 4)));
        #pragma unroll
        for (int m = 0; m < 4; ++m) {
            int r = m * 16 + lr;
            bf16x8 af = *(const bf16x8*)(As + ((r * 128 + koff) ^ ((lr & 7) << 4)));
            acc[m] = __builtin_amdgcn_mfma_f32_16x16x32_bf16(af, bfv, acc[m], 0, 0, 0);
        }
    }
}

__device__ __forceinline__ void gemm64_core(
    const unsigned short* __restrict__ A, const unsigned short* __restrict__ W,
    const float* __restrict__ bias, const float* __restrict__ residf,
    const unsigned short* __restrict__ residb,
    float* __restrict__ Cf, unsigned short* __restrict__ Cb,
    int N, int K, int relu, int row0, int col0)
{
    __shared__ char ldsb[32768];               // dbuf staging; reused as fp32 T
    char* As0 = ldsb;          char* Bs0 = ldsb + 8192;
    char* As1 = ldsb + 16384;  char* Bs1 = ldsb + 24576;

    const int t = threadIdx.x;
    const int w = t >> 6, l = t & 63;
    const int lr = l & 15, lg = l >> 4;

    f32x4 acc[4] = {};

    stage_tile(A, row0, 0, K, As0, t);
    stage_tile(W, col0, 0, K, Bs0, t);
    __syncthreads();

    const int NK = K >> 6;
    int buf = 0;
    for (int ks = 0; ks < NK; ++ks) {
        if (ks + 1 < NK) {
            stage_tile(A, row0, (ks + 1) * 64, K, buf ? As0 : As1, t);
            stage_tile(W, col0, (ks + 1) * 64, K, buf ? Bs0 : Bs1, t);
        }
        compute_strip(buf ? As1 : As0, buf ? Bs1 : Bs0, acc, w, lr, lg);
        __syncthreads();
        buf ^= 1;
    }

    // epilogue: transpose through LDS -> coalesced stores
    float* T = (float*)ldsb;                    // [64][65] fp32
    #pragma unroll
    for (int m = 0; m < 4; ++m)
        #pragma unroll
        for (int r = 0; r < 4; ++r)
            T[(m * 16 + lg * 4 + r) * 65 + w * 16 + lr] =
                acc[m][r] + bias[col0 + w * 16 + lr];
    __syncthreads();

    #pragma unroll
    for (int i = 0; i < 4; ++i) {
        int idx = t + i * 256;
        int row = idx >> 4, c4 = idx & 15;
        float v0 = T[row * 65 + c4 * 4 + 0];
        float v1 = T[row * 65 + c4 * 4 + 1];
        float v2 = T[row * 65 + c4 * 4 + 2];
        float v3 = T[row * 65 + c4 * 4 + 3];
        size_t goff = (size_t)(row0 + row) * N + col0 + c4 * 4;
        if (residf) {
            float4 rv = *(const float4*)(residf + goff);
            v0 += rv.x; v1 += rv.y; v2 += rv.z; v3 += rv.w;
        }
        if (residb) {
            uint2 rb = *(const uint2*)(residb + goff);
            v0 += bf2f((unsigned short)(rb.x & 0xFFFF));
            v1 += bf2f((unsigned short)(rb.x >> 16));
            v2 += bf2f((unsigned short)(rb.y & 0xFFFF));
            v3 += bf2f((unsigned short)(rb.y >> 16));
        }
        if (relu) {
            v0 = fmaxf(v0, 0.f); v1 = fmaxf(v1, 0.f);
            v2 = fmaxf(v2, 0.f); v3 = fmaxf(v3, 0.f);
        }
        if (Cb) *(uint2*)(Cb + goff) = make_uint2(packbf(v0, v1), packbf(v2, v3));
        else    *(float4*)(Cf + goff) = make_float4(v0, v1, v2, v3);
    }
}

__global__ __launch_bounds__(256) void gemm_b16(
    const unsigned short* __restrict__ A, const unsigned short* __restrict__ W,
    const float* __restrict__ bias, const float* __restrict__ residf,
    const unsigned short* __restrict__ residb,
    float* __restrict__ Cf, unsigned short* __restrict__ Cb,
    int N, int K, int relu)
{
    gemm64_core(A, W, bias, residf, residb, Cf, Cb, N, K, relu,
                blockIdx.x * 64, blockIdx.y * 64);
}

__global__ __launch_bounds__(256) void gemm_qkv3(
    const unsigned short* __restrict__ qkvb, const unsigned short* __restrict__ Wt,
    const float* __restrict__ bq, const float* __restrict__ bk,
    const float* __restrict__ bv, unsigned short* __restrict__ outb)
{
    const int z = blockIdx.z;
    const unsigned short* A = qkvb + (size_t)z * 4096 * 1024;
    const unsigned short* W = Wt + (size_t)z * 262144;
    const float* bias = (z == 0) ? bq : ((z == 1) ? bk : bv);
    unsigned short* Cb = outb + (size_t)z * 4096 * 256;
    gemm64_core(A, W, bias, nullptr, nullptr, nullptr, Cb, 256, 1024, 0,
                blockIdx.x * 64, blockIdx.y * 64);
}

// ---------------------------------------------------------------------------
// Weight prep: fp32 [K][N] -> bf16 [N][K], all 6 weights in one launch.
// ---------------------------------------------------------------------------
__global__ __launch_bounds__(256) void prep_w(
    const float* __restrict__ Wq, const float* __restrict__ Wk,
    const float* __restrict__ Wv, const float* __restrict__ Wo,
    const float* __restrict__ W1, const float* __restrict__ W2,
    unsigned short* __restrict__ Wt)
{
    __shared__ float tile[64][65];
    const int bid = blockIdx.x;
    const float* src; int K, N; size_t off; int local;
    if (bid < 64)       { src = Wq; K = 1024; N = 256;  off = 0;        local = bid; }
    else if (bid < 128) { src = Wk; K = 1024; N = 256;  off = 262144;  local = bid - 64; }
    else if (bid < 192) { src = Wv; K = 1024; N = 256;  off = 524288;  local = bid - 128; }
    else if (bid < 256) { src = Wo; K = 256;  N = 1024; off = 786432;  local = bid - 192; }
    else if (bid < 384) { src = W1; K = 1024; N = 512;  off = 1048576; local = bid - 256; }
    else                { src = W2; K = 512;  N = 1024; off = 1572864; local = bid - 384; }
    const int nkt = K >> 6;
    const int k0 = (local % nkt) * 64, n0 = (local / nkt) * 64;
    const int t = threadIdx.x;
    #pragma unroll
    for (int i = 0; i < 16; ++i) {
        int id = t + i * 256;
        int r = id >> 6, c = id & 63;
        tile[r][c] = src[(size_t)(k0 + r) * N + n0 + c];
    }
    __syncthreads();
    unsigned* Wt32 = (unsigned*)(Wt + off);
    #pragma unroll
    for (int i = 0; i < 8; ++i) {
        int id = t + i * 256;
        int n = id >> 5, ku = id & 31;
        Wt32[((size_t)(n0 + n) * K + k0) / 2 + ku] =
            packbf(tile[2 * ku][n], tile[2 * ku + 1][n]);
    }
}

// q,k,v fp32 -> bf16 contiguous [3][4096][1024]
__global__ __launch_bounds__(256) void prep_qkv(
    const float* __restrict__ q, const float* __restrict__ k,
    const float* __restrict__ v, unsigned short* __restrict__ qkvb)
{
    const float* src = blockIdx.z == 0 ? q : (blockIdx.z == 1 ? k : v);
    uint2* dst = (uint2*)(qkvb + (size_t)blockIdx.z * 4096 * 1024);
    int idx = blockIdx.x * 256 + threadIdx.x;
    float4 x = ((const float4*)src)[idx];
    dst[idx] = make_uint2(packbf(x.x, x.y), packbf(x.z, x.w));
}

// Vb [b][s][h*64+d] bf16 -> Vt [bh][d][s] bf16
__global__ __launch_bounds__(256) void prep_v(const unsigned short* __restrict__ Vb,
                                              unsigned short* __restrict__ Vt)
{
    __shared__ unsigned Vl[64][34];
    const int k0 = blockIdx.x * 64;
    const int bh = blockIdx.y;
    const int b = bh >> 2, h = bh & 3;
    const int t = threadIdx.x;
    const unsigned* Vg = (const unsigned*)Vb + (size_t)(b * S_LEN) * 128 + h * 32;
    #pragma unroll
    for (int i = 0; i < 8; ++i) {
        int id = t + i * 256;
        int key = id >> 5, cu = id & 31;
        Vl[key][cu] = Vg[(size_t)(k0 + key) * 128 + cu];
    }
    __syncthreads();
    const unsigned short* Vl16 = (const unsigned short*)Vl;
    unsigned* Vo = (unsigned*)Vt + (size_t)bh * 65536;
    #pragma unroll
    for (int i = 0; i < 8; ++i) {
        int id = t + i * 256;
        int d = id >> 5, ku = id & 31;
        unsigned lo = Vl16[(2 * ku) * 68 + d];
        unsigned hi = Vl16[(2 * ku + 1) * 68 + d];
        Vo[(size_t)d * 1024 + (k0 >> 1) + ku] = lo | (hi << 16);
    }
}

// ---------------------------------------------------------------------------
// Global attention, split-K flash. 1-D grid 1024, XCD-swizzled block remap.
// Each block: 64 q-rows x 512 keys (8 tiles). K/V reg-prefetch (T14).
// Epilogue: O transposed through LDS -> coalesced 256B-row stores.
// ---------------------------------------------------------------------------
__global__ __launch_bounds__(256) void attn_global_split(
    const unsigned short* __restrict__ Qb, const unsigned short* __restrict__ Kb,
    const unsigned short* __restrict__ Vt, const float* __restrict__ adj_w,
    const float* __restrict__ adj_b, float* __restrict__ Opart,
    float* __restrict__ mlpart)
{
    __shared__ unsigned shmem[6144];     // Kl[2048] | Vl[2048] | Pl[4][512]
    unsigned* Kl = shmem;
    unsigned* Vl = shmem + 2048;
    unsigned* Pl = shmem + 4096;

    // XCD-aware remap: consecutive lid share (bh,ck) on one XCD
    const int bid = blockIdx.x;                   // 0..1023
    const int lid = (bid & 7) * 128 + (bid >> 3);
    const int q0 = (lid & 31) * 64;
    const int bh = (lid >> 5) & 7;
    const int ck = lid >> 8;
    const int b = bh >> 2, h = bh & 3;
    const int t = threadIdx.x;
    const int w = t >> 6, l = t & 63;
    const int lr = l & 15, lg = l >> 4;
    const float aw = adj_w[0], ab = adj_b[0];

    const int qrow = q0 + w * 16 + lr;
    const unsigned* qb32 = (const unsigned*)Qb + (size_t)(b * S_LEN + qrow) * 128 + h * 32;
    bf16x8 qf[2];
    #pragma unroll
    for (int hh = 0; hh < 2; ++hh) {
        union { unsigned u[4]; bf16x8 v; } tmpu;
        #pragma unroll
        for (int jj = 0; jj < 4; ++jj) tmpu.u[jj] = qb32[hh * 16 + lg * 4 + jj];
        qf[hh] = tmpu.v;
    }

    const unsigned* Kg = (const unsigned*)Kb + (size_t)(b * S_LEN) * 128 + h * 32;
    const unsigned* Vg = (const unsigned*)Vt + (size_t)bh * 65536;
    const int kbase = ck * 512;

    float mrow = -1e30f, lrow = 0.f;
    f32x4 o[4] = {};
    uint4 rk[2], rv[2];

    #pragma unroll
    for (int i = 0; i < 2; ++i) {
        int id4 = t + i * 256;
        int r4 = id4 >> 3, c4 = id4 & 7;
        rk[i] = *(const uint4*)(Kg + (size_t)(kbase + r4) * 128 + c4 * 4);
        rv[i] = *(const uint4*)(Vg + (size_t)r4 * 1024 + (kbase >> 1) + c4 * 4);
    }
    #pragma unroll
    for (int i = 0; i < 2; ++i) {
        int id4 = t + i * 256;
        int r4 = id4 >> 3, c4 = id4 & 7;
        *(uint4*)((char*)Kl + swz(r4 * 128 + c4 * 16)) = rk[i];
        *(uint4*)((char*)Vl + swz(r4 * 128 + c4 * 16)) = rv[i];
    }

    for (int tt = 0; tt < 8; ++tt) {
        const int k0 = kbase + tt * 64;
        __syncthreads();
        if (tt < 7) {
            const int kn = k0 + 64;
            #pragma unroll
            for (int i = 0; i < 2; ++i) {
                int id4 = t + i * 256;
                int r4 = id4 >> 3, c4 = id4 & 7;
                rk[i] = *(const uint4*)(Kg + (size_t)(kn + r4) * 128 + c4 * 4);
                rv[i] = *(const uint4*)(Vg + (size_t)r4 * 1024 + (kn >> 1) + c4 * 4);
            }
        }

        float sv[4][4];
        #pragma unroll
        for (int f = 0; f < 4; ++f) {
            int krow = f * 16 + lr;
            bf16x8 kf0 = *(const bf16x8*)((const char*)Kl + swz(krow * 128 + lg * 16));
            bf16x8 kf1 = *(const bf16x8*)((const char*)Kl + swz(krow * 128 + lg * 16 + 64));
            f32x4 stf = {0.f, 0.f, 0.f, 0.f};
            stf = __builtin_amdgcn_mfma_f32_16x16x32_bf16(kf0, qf[0], stf, 0, 0, 0);
            stf = __builtin_amdgcn_mfma_f32_16x16x32_bf16(kf1, qf[1], stf, 0, 0, 0);
            int klo = k0 + f * 16;
            bool near = (q0 + w * 16 + 15 >= klo - 6) && (q0 + w * 16 <= klo + 21);
            #pragma unroll
            for (int r = 0; r < 4; ++r) {
                float x = stf[r] * ATT_SCALE;
                if (near) {
                    int key = klo + lg * 4 + r;
                    float dd = (float)(qrow - key);
                    x += __expf(-fabsf(aw * dd * dd - ab));
                }
                sv[f][r] = x;
            }
        }

        float tmax = -1e30f;
        #pragma unroll
        for (int f = 0; f < 4; ++f)
            #pragma unroll
            for (int r = 0; r < 4; ++r) tmax = fmaxf(tmax, sv[f][r]);
        tmax = fmaxf(tmax, __shfl_xor(tmax, 16, 64));
        tmax = fmaxf(tmax, __shfl_xor(tmax, 32, 64));
        float mnew = fmaxf(mrow, tmax);
        float fac  = __expf(mrow - mnew);
        float ts = 0.f;
        #pragma unroll
        for (int f = 0; f < 4; ++f)
            #pragma unroll
            for (int r = 0; r < 4; ++r) {
                float p = __expf(sv[f][r] - mnew);
                sv[f][r] = p; ts += p;
            }
        ts += __shfl_xor(ts, 16, 64);
        ts += __shfl_xor(ts, 32, 64);
        lrow = lrow * fac + ts;
        mrow = mnew;
        #pragma unroll
        for (int rf = 0; rf < 4; ++rf) o[rf] *= fac;

        #pragma unroll
        for (int f = 0; f < 4; ++f) {
            uint2 pw;
            pw.x = packbf(sv[f][0], sv[f][1]);
            pw.y = packbf(sv[f][2], sv[f][3]);
            *(uint2*)((char*)(Pl + w * 512) + swz(lr * 128 + f * 32 + lg * 8)) = pw;
        }

        #pragma unroll
        for (int hh = 0; hh < 2; ++hh) {
            bf16x8 pf = *(const bf16x8*)((const char*)(Pl + w * 512) + swz(lr * 128 + lg * 16 + 64 * hh));
            #pragma unroll
            for (int rf = 0; rf < 4; ++rf) {
                int vrow = rf * 16 + lr;
                bf16x8 vf = *(const bf16x8*)((const char*)Vl + swz(vrow * 128 + lg * 16 + 64 * hh));
                o[rf] = __builtin_amdgcn_mfma_f32_16x16x32_bf16(vf, pf, o[rf], 0, 0, 0);
            }
        }
        __syncthreads();
        if (tt < 7) {
            #pragma unroll
            for (int i = 0; i < 2; ++i) {
                int id4 = t + i * 256;
                int r4 = id4 >> 3, c4 = id4 & 7;
                *(uint4*)((char*)Kl + swz(r4 * 128 + c4 * 16)) = rk[i];
                *(uint4*)((char*)Vl + swz(r4 * 128 + c4 * 16)) = rv[i];
            }
        }
    }

    // mlpart (small)
    const size_t idx = (size_t)(ck * 8 + bh) * 2048 + qrow;
    if (lg == 0) {
        mlpart[idx * 2]     = mrow;
        mlpart[idx * 2 + 1] = lrow;
    }

    // coalesced Opart epilogue: transpose via LDS [64][68] fp32 (17KB < 24KB)
    __syncthreads();                     // all waves done with Kl/Vl/Pl
    float* T = (float*)shmem;
    #pragma unroll
    for (int rf = 0; rf < 4; ++rf)
        *(float4*)(T + (w * 16 + lr) * 68 + rf * 16 + lg * 4) =
            make_float4(o[rf][0], o[rf][1], o[rf][2], o[rf][3]);
    __syncthreads();
    float* obase = Opart + ((size_t)(ck * 8 + bh) * 2048 + q0) * 64;
    #pragma unroll
    for (int i = 0; i < 4; ++i) {
        int id = t + i * 256;            // 0..1023 float4 units
        int row = id >> 4, c4 = id & 15;
        *(float4*)(obase + row * 64 + c4 * 4) =
            *(const float4*)(T + row * 68 + c4 * 4);
    }
}

// ---------------------------------------------------------------------------
// Merge split-K partials + LOCAL windowed attention (fused) + mix + signed
// sqrt -> tmpb bf16. grid = B*S blocks of 256; wave = head, lane = dh.
// ---------------------------------------------------------------------------
__global__ __launch_bounds__(256) void attn_combine(
    const float* __restrict__ Opart, const float* __restrict__ mlpart,
    const unsigned short* __restrict__ Qb, const unsigned short* __restrict__ Kb,
    const unsigned short* __restrict__ Vb, const float* __restrict__ alpha,
    const float* __restrict__ adj_w, const float* __restrict__ adj_b,
    unsigned short* __restrict__ tmpb)
{
    const int row = blockIdx.x;            // b*2048 + s
    const int b = row >> 11;
    const int s = row & 2047;
    const int h = threadIdx.x >> 6;
    const int lane = threadIdx.x & 63;
    const float w = adj_w[0], bb = adj_b[0];

    // local windowed attention (WIN=9, clipped indices dedup'd)
    const float qd = bf2f(Qb[(size_t)row * HID + h * 64 + lane]);
    float sc[9]; int cls[9];
    float mx = -1e30f; int prev = -1;
    #pragma unroll
    for (int kk = 0; kk < 9; ++kk) {
        int c = s - 4 + kk;
        c = c < 0 ? 0 : (c > S_LEN - 1 ? S_LEN - 1 : c);
        bool valid = (c != prev);
        prev = c;
        float kd = bf2f(Kb[(size_t)(b * S_LEN + c) * HID + h * 64 + lane]);
        float part = qd * kd;
        #pragma unroll
        for (int off = 32; off; off >>= 1) part += __shfl_xor(part, off, 64);
        float dd = fabsf((float)(s - c));
        float vv = part * ATT_SCALE + expf(-fabsf(w * dd * dd - bb));
        sc[kk]  = valid ? vv : -1e30f;
        cls[kk] = c;
        mx = fmaxf(mx, sc[kk]);
    }
    float sum = 0.f;
    #pragma unroll
    for (int kk = 0; kk < 9; ++kk) { sc[kk] = expf(sc[kk] - mx); sum += sc[kk]; }
    float lval = 0.f;
    #pragma unroll
    for (int kk = 0; kk < 9; ++kk)
        lval += sc[kk] * bf2f(Vb[(size_t)(b * S_LEN + cls[kk]) * HID + h * 64 + lane]);
    lval /= sum;

    // global split-K merge
    const size_t base = (size_t)(b * NH + h) * 2048 + s;
    float mv[4], lv[4];
    float M = -1e30f;
    #pragma unroll
    for (int ck = 0; ck < 4; ++ck) {
        mv[ck] = mlpart[(ck * 16384 + base) * 2];
        lv[ck] = mlpart[(ck * 16384 + base) * 2 + 1];
        M = fmaxf(M, mv[ck]);
    }
    float O = 0.f, L = 0.f;
    #pragma unroll
    for (int ck = 0; ck < 4; ++ck) {
        float e = __expf(mv[ck] - M);
        O += e * Opart[(ck * 16384 + base) * 64 + lane];
        L += e * lv[ck];
    }
    float g = O / L;
    float a = 1.f / (1.f + expf(-alpha[0]));
    float x = a * g + (1.f - a) * lval;
    float r = x > 0.f ? sqrtf(x) : (x < 0.f ? -sqrtf(-x) : 0.f);
    tmpb[(size_t)row * HID + h * 64 + lane] = f2bf(r);
}

// ---------------------------------------------------------------------------
// partial column sums of squares: 256 blocks = (b, s-chunk of 16), LDS-staged.
__global__ __launch_bounds__(256) void colnorm_part(
    const unsigned short* __restrict__ tmpb, float* __restrict__ part)
{
    __shared__ unsigned short Tl[16][256];
    const int b = blockIdx.x >> 7, ch = blockIdx.x & 127;
    const int t = threadIdx.x;
    const uint4* src = (const uint4*)(tmpb + ((size_t)b * S_LEN + ch * 16) * HID);
    #pragma unroll
    for (int i = 0; i < 2; ++i) {
        int idx = t + i * 256;
        ((uint4*)Tl)[idx] = src[idx];
    }
    __syncthreads();
    float ss = 0.f;
    #pragma unroll
    for (int r = 0; r < 16; ++r) {
        float v2 = bf2f(Tl[r][t]);
        ss += v2 * v2;
    }
    part[blockIdx.x * 256 + t] = ss;
}

// 512 blocks (b*256+c) x 64 threads: wave-reduce 128 partials each
__global__ __launch_bounds__(64) void colnorm_fin(
    const float* __restrict__ part, float* __restrict__ inv_nrm)
{
    const int bc = blockIdx.x;
    const int b = bc >> 8, c = bc & 255;
    const int j = threadIdx.x;
    float s = part[(b * 128 + j) * 256 + c] + part[(b * 128 + j + 64) * 256 + c];
    #pragma unroll
    for (int off = 32; off; off >>= 1) s += __shfl_xor(s, off, 64);
    if (j == 0) inv_nrm[bc] = 1.f / fmaxf(sqrtf(s), 1e-12f);
}

__global__ __launch_bounds__(256) void scale_inv(
    unsigned short* __restrict__ tmpb, const float* __restrict__ inv_nrm)
{
    int idx = blockIdx.x * 256 + threadIdx.x;
    int c = idx & 255, b = idx >> 19;
    tmpb[idx] = f2bf(bf2f(tmpb[idx]) * inv_nrm[b * 256 + c]);
}

// ---------------------------------------------------------------------------
// LayerNorm over last dim (1024). Optional fp32 and/or bf16 outputs.
// ---------------------------------------------------------------------------
__global__ __launch_bounds__(256) void layernorm_k(
    const float* __restrict__ x, const float* __restrict__ g,
    const float* __restrict__ be, float* __restrict__ outf,
    unsigned short* __restrict__ outb)
{
    const int row = blockIdx.x;
    const float4 xv = ((const float4*)(x + (size_t)row * DMODEL))[threadIdx.x];
    float s  = xv.x + xv.y + xv.z + xv.w;
    float ss = xv.x * xv.x + xv.y * xv.y + xv.z * xv.z + xv.w * xv.w;
    #pragma unroll
    for (int off = 32; off; off >>= 1) {
        s  += __shfl_xor(s,  off, 64);
        ss += __shfl_xor(ss, off, 64);
    }
    __shared__ float rs[4], rss[4];
    if ((threadIdx.x & 63) == 0) { rs[threadIdx.x >> 6] = s; rss[threadIdx.x >> 6] = ss; }
    __syncthreads();
    s  = rs[0] + rs[1] + rs[2] + rs[3];
    ss = rss[0] + rss[1] + rss[2] + rss[3];
    const float mu  = s * (1.f / DMODEL);
    const float var = ss * (1.f / DMODEL) - mu * mu;
    const float r   = rsqrtf(var + LN_EPS);
    const float4 gv = ((const float4*)g)[threadIdx.x];
    const float4 bv = ((const float4*)be)[threadIdx.x];
    float4 ov;
    ov.x = (xv.x - mu) * r * gv.x + bv.x;
    ov.y = (xv.y - mu) * r * gv.y + bv.y;
    ov.z = (xv.z - mu) * r * gv.z + bv.z;
    ov.w = (xv.w - mu) * r * gv.w + bv.w;
    if (outf) ((float4*)(outf + (size_t)row * DMODEL))[threadIdx.x] = ov;
    if (outb) {
        unsigned* ob = (unsigned*)(outb + (size_t)row * DMODEL);
        ob[threadIdx.x * 2]     = packbf(ov.x, ov.y);
        ob[threadIdx.x * 2 + 1] = packbf(ov.z, ov.w);
    }
}

// ---------------------------------------------------------------------------
extern "C" void kernel_launch(void* const* d_in, const int* in_sizes, int n_in,
                              void* d_out, int out_size, void* d_ws, size_t ws_size,
                              hipStream_t stream)
{
    const float* q     = (const float*)d_in[0];
    const float* k     = (const float*)d_in[1];
    const float* v     = (const float*)d_in[2];
    const float* Wq    = (const float*)d_in[3];
    const float* bq    = (const float*)d_in[4];
    const float* Wk    = (const float*)d_in[5];
    const float* bk    = (const float*)d_in[6];
    const float* Wv    = (const float*)d_in[7];
    const float* bv    = (const float*)d_in[8];
    const float* Wo    = (const float*)d_in[9];
    const float* bo    = (const float*)d_in[10];
    const float* alpha = (const float*)d_in[11];
    const float* adj_w = (const float*)d_in[12];
    const float* adj_b = (const float*)d_in[13];
    const float* W1    = (const float*)d_in[14];
    const float* b1    = (const float*)d_in[15];
    const float* W2    = (const float*)d_in[16];
    const float* b2    = (const float*)d_in[17];
    const float* g1    = (const float*)d_in[18];
    const float* be1   = (const float*)d_in[19];
    const float* g2    = (const float*)d_in[20];
    const float* be2   = (const float*)d_in[21];

    const int ROWS = B_SZ * S_LEN;     // 4096

    // Workspace layout (bytes):
    char* WS = (char*)d_ws;
    float*          x1     = (float*)WS;
    float*          Opart  = (float*)WS;                                 // 16MB
    unsigned short* qkvb   = (unsigned short*)WS;                        // 24MB
    float*          mlpart = (float*)(WS + (16u << 20));                 // 512KB
    unsigned short* xlnb   = (unsigned short*)(WS + (16u << 20));        // 8MB
    unsigned short* Qb     = (unsigned short*)(WS + (28u << 20));
    unsigned short* Kb     = (unsigned short*)(WS + (30u << 20));
    unsigned short* Vb     = (unsigned short*)(WS + (32u << 20));
    unsigned short* Vt     = (unsigned short*)(WS + (34u << 20));
    unsigned short* tmpb   = (unsigned short*)(WS + (36u << 20));
    float*          invn   = (float*)(WS + (38u << 20));
    float*          part   = (float*)(WS + (38u << 20) + 4096);
    unsigned short* Wt     = (unsigned short*)(WS + (39u << 20));
    unsigned short* hbufb  = (unsigned short*)(WS + (28u << 20));        // alias Qb/Kb

    // 1. weight transpose + bf16
    prep_w<<<dim3(512), dim3(256), 0, stream>>>(Wq, Wk, Wv, Wo, W1, W2, Wt);
    // 2. q,k,v -> bf16
    prep_qkv<<<dim3(4096, 1, 3), dim3(256), 0, stream>>>(q, k, v, qkvb);
    // 3. QKV projections -> Qb/Kb/Vb bf16
    gemm_qkv3<<<dim3(64, 4, 3), dim3(256), 0, stream>>>(qkvb, Wt, bq, bk, bv, Qb);
    // 4. V transpose
    prep_v<<<dim3(32, 8), dim3(256), 0, stream>>>(Vb, Vt);
    // 5. attention (split-K x4, XCD-swizzled 1-D grid)
    attn_global_split<<<dim3(1024), dim3(256), 0, stream>>>(Qb, Kb, Vt, adj_w, adj_b,
                                                            Opart, mlpart);
    // 6. merge partials + local attention + mix + signed sqrt -> tmpb
    attn_combine<<<dim3(4096), dim3(256), 0, stream>>>(Opart, mlpart, Qb, Kb, Vb,
                                                       alpha, adj_w, adj_b, tmpb);
    // 7. L2 norm over sequence axis
    colnorm_part<<<dim3(256), dim3(256), 0, stream>>>(tmpb, part);
    colnorm_fin<<<dim3(512), dim3(64), 0, stream>>>(part, invn);
    scale_inv<<<dim3(4096), dim3(256), 0, stream>>>(tmpb, invn);
    // 8. attn_out = tmpb @ Wo + bo + q -> x1 (fp32)
    gemm_b16<<<dim3(64, 16), dim3(256), 0, stream>>>(tmpb, Wt + 786432, bo, q, nullptr,
                                                     x1, nullptr, DMODEL, HID, 0);
    // 9. LN1 -> xlnb (bf16)
    layernorm_k<<<dim3(ROWS), dim3(256), 0, stream>>>(x1, g1, be1, nullptr, xlnb);
    // 10. FFN1 -> hbufb (bf16, relu)
    gemm_b16<<<dim3(64, 8), dim3(256), 0, stream>>>(xlnb, Wt + 1048576, b1, nullptr, nullptr,
                                                    nullptr, hbufb, DFF, DMODEL, 1);
    // 11. FFN2 + resid xlnb -> x1 (fp32)
    gemm_b16<<<dim3(64, 16), dim3(256), 0, stream>>>(hbufb, Wt + 1572864, b2, nullptr, xlnb,
                                                     x1, nullptr, DMODEL, DFF, 0);
    // 12. LN2 -> output
    layernorm_k<<<dim3(ROWS), dim3(256), 0, stream>>>(x1, g2, be2, (float*)d_out, nullptr);
}